// Round 8
// baseline (22.243 us; speedup 1.0000x reference)
//
#include <hip/hip_runtime.h>
#include <math.h>

// PolyIoULoss closed-form, ONE fat dispatch + 72-byte memset node.
//
// Reduction: hierarchical fixed-point integer atomic tree.
//  - block partial (f32, deterministic in-block order) -> exact fixed point:
//    fx = llrint((double)s * 2^26). Integer adds are exactly commutative =>
//    bitwise-deterministic final sum regardless of block arrival order.
//  - u64 accumulator packs {arrival count @bit56 | sum in low 56 bits}.
//    Stage 1: acc[blockIdx & 7]  (~64 contenders/address; blockIdx%8 == XCD
//    under round-robin dispatch, so contention stays local-ish).
//    Stage 2: group-last forwards group total to final (8 contenders);
//    8th forwarder writes out. No winner re-read pass, no cache flushes.
//  R4/R7 lesson: a SINGLE counter with >=512 synchronized blocks serializes
//  same-address RMWs (~27ns each => 14-60us). 64-way max contention here.
//
// Area(P∩T) via Green's theorem: each clipped edge contributes
// (t1-t0)*cross(A,r); cross(A,r) collapses to per-box constants plus offset
// corrections (components of R(psi)*tc). t0/t1 via Liang-Barsky against an
// AABB in the other box's local frame. Branchless; IEEE inf handles
// parallel edges. ITEMS=4 (512 blocks) — measured best.

#define BS 256
#define ITEMS 4

#define FP_SCALE 67108864.0      // 2^26
#define CNT_ONE  (1ULL << 56)
#define SUM_MASK (CNT_ONE - 1)

__device__ __forceinline__ float lb_delta(float Ax, float Ay,
                                          float irx, float iry,
                                          float hw, float hh)
{
    // Liang-Barsky span of segment A + t*r, t in [0,1], vs |x|<=hw,|y|<=hh
    const float tA = (-hw - Ax) * irx;
    const float tB = ( hw - Ax) * irx;
    const float tC = (-hh - Ay) * iry;
    const float tD = ( hh - Ay) * iry;
    const float tx0 = fminf(tA, tB), tx1 = fmaxf(tA, tB);
    const float ty0 = fminf(tC, tD), ty1 = fmaxf(tC, tD);
    const float t0 = fmaxf(fmaxf(tx0, ty0), 0.0f);   // v_max3
    const float t1 = fminf(fminf(tx1, ty1), 1.0f);   // v_min3
    return fmaxf(t1 - t0, 0.0f);
}

__device__ __forceinline__ float pair_loss(const float* __restrict__ pp,
                                           const float* __restrict__ tp)
{
    const float pcx = pp[0], pcy = pp[1], pw = pp[2], ph = pp[3], phi = pp[4];
    const float tcx = tp[0] - pcx, tcy = tp[1] - pcy;   // pred-centered frame
    const float tw = tp[2], th = tp[3], psi = tp[4];

    const float a1 = 0.5f * pw, b1 = 0.5f * ph;
    const float a2 = 0.5f * tw, b2 = 0.5f * th;

    float sphi, cphi, spsi, cpsi;
    __sincosf(phi, &sphi, &cphi);
    __sincosf(psi, &spsi, &cpsi);
    // delta = psi - phi
    const float cd = cpsi * cphi + spsi * sphi;
    const float sd = spsi * cphi - cpsi * sphi;

    // ---- P edges in T-local frame; clipper AABB (a2,b2) ----
    const float Cx = cpsi * tcx - spsi * tcy;
    const float Cy = spsi * tcx + cpsi * tcy;
    const float Xx = a1 * cd,  Xy = a1 * sd;
    const float Yx = -b1 * sd, Yy = b1 * cd;
    const float i0x = __builtin_amdgcn_rcpf(2.0f * Xx);
    const float i0y = __builtin_amdgcn_rcpf(2.0f * Xy);
    const float i1x = __builtin_amdgcn_rcpf(2.0f * Yx);
    const float i1y = __builtin_amdgcn_rcpf(2.0f * Yy);

    const float dP0 = lb_delta(-Xx - Yx - Cx, -Xy - Yy - Cy,  i0x,  i0y, a2, b2);
    const float dP1 = lb_delta( Xx - Yx - Cx,  Xy - Yy - Cy,  i1x,  i1y, a2, b2);
    const float dP2 = lb_delta( Xx + Yx - Cx,  Xy + Yy - Cy, -i0x, -i0y, a2, b2);
    const float dP3 = lb_delta(-Xx + Yx - Cx, -Xy + Yy - Cy, -i1x, -i1y, a2, b2);
    const float sumP = (dP0 + dP1) + (dP2 + dP3);

    // ---- T edges in P-local frame; clipper AABB (a1,b1) ----
    const float C2x = cphi * tcx - sphi * tcy;
    const float C2y = sphi * tcx + cphi * tcy;
    const float Xpx = a2 * cd,  Xpy = -a2 * sd;
    const float Ypx = b2 * sd,  Ypy = b2 * cd;
    const float j0x = __builtin_amdgcn_rcpf(2.0f * Xpx);
    const float j0y = __builtin_amdgcn_rcpf(2.0f * Xpy);
    const float j1x = __builtin_amdgcn_rcpf(2.0f * Ypx);
    const float j1y = __builtin_amdgcn_rcpf(2.0f * Ypy);

    const float dT0 = lb_delta(C2x - Xpx - Ypx, C2y - Xpy - Ypy,  j0x,  j0y, a1, b1);
    const float dT1 = lb_delta(C2x + Xpx - Ypx, C2y + Xpy - Ypy,  j1x,  j1y, a1, b1);
    const float dT2 = lb_delta(C2x + Xpx + Ypx, C2y + Xpy + Ypy, -j0x, -j0y, a1, b1);
    const float dT3 = lb_delta(C2x - Xpx + Ypx, C2y - Xpy + Ypy, -j1x, -j1y, a1, b1);
    const float sumT = (dT0 + dT1) + (dT2 + dT3);

    float area = a1 * b1 * sumP + a2 * b2 * sumT
               - a2 * Cy * (dT0 - dT2) + b2 * Cx * (dT1 - dT3);
    area = fmaxf(area, 0.0f);

    const float A1 = pw * ph, A2 = tw * th;
    const float iou = fmaxf(area / (A1 + A2 - area + 1e-6f), 1e-6f);
    return -__logf(iou);
}

__global__ __launch_bounds__(BS) void poly_iou_fused(
    const float* __restrict__ pred, const float* __restrict__ tgt,
    unsigned long long* __restrict__ acc,    // acc[0..7] stage-1, acc[8] final
    float* __restrict__ out, int n, int nblocks, double inv_n)
{
    const int tid = threadIdx.x;
    const int stride = gridDim.x * BS;

    float loss = 0.0f;
#pragma unroll
    for (int it = 0; it < ITEMS; ++it) {
        const int gid = blockIdx.x * BS + tid + it * stride;
        if (gid < n)
            loss += pair_loss(pred + (long)gid * 5, tgt + (long)gid * 5);
    }

    // block reduction (wave shuffle + tiny LDS), deterministic in-block order
#pragma unroll
    for (int off = 32; off > 0; off >>= 1) loss += __shfl_down(loss, off);
    __shared__ float wsum[BS / 64];
    if ((tid & 63) == 0) wsum[tid >> 6] = loss;
    __syncthreads();
    if (tid == 0) {
        float s = 0.0f;
#pragma unroll
        for (int w = 0; w < BS / 64; ++w) s += wsum[w];
        s = fmaxf(s, 0.0f);   // guard count-field corruption (loss >= 0 anyway)
        // exact: s has 24-bit mantissa, *2^26 exact in double, llrint exact
        const unsigned long long fx =
            (unsigned long long)llrint((double)s * FP_SCALE);

        const int g = blockIdx.x & 7;                   // == XCD id (round-robin)
        const unsigned long long cnt_g =
            (unsigned long long)((nblocks - 1 - g) / 8 + 1);
        const unsigned long long old1 = atomicAdd(&acc[g], fx + CNT_ONE);
        if ((old1 >> 56) == cnt_g - 1) {
            // last arrival in this group: forward group total
            const unsigned long long t1 = (old1 & SUM_MASK) + fx;
            const int ngroups = nblocks < 8 ? nblocks : 8;
            const unsigned long long old2 = atomicAdd(&acc[8], t1 + CNT_ONE);
            if ((old2 >> 56) == (unsigned long long)(ngroups - 1)) {
                // global last: grand total from returned old + own forward
                const unsigned long long tot = (old2 & SUM_MASK) + t1;
                out[0] = (float)((double)tot * (1.0 / FP_SCALE) * inv_n);
            }
        }
    }
}

extern "C" void kernel_launch(void* const* d_in, const int* in_sizes, int n_in,
                              void* d_out, int out_size, void* d_ws, size_t ws_size,
                              hipStream_t stream) {
    const float* pred = (const float*)d_in[0];
    const float* tgt  = (const float*)d_in[1];
    float* out = (float*)d_out;
    const int n = in_sizes[0] / 5;
    const int nblocks = (n + BS * ITEMS - 1) / (BS * ITEMS);

    unsigned long long* acc = (unsigned long long*)d_ws;

    // accumulators must be 0 at kernel start on EVERY call (ws poisoned once
    // before timing, never re-poisoned; tiny memset node is capture-legal).
    hipMemsetAsync(acc, 0, 9 * sizeof(unsigned long long), stream);

    hipLaunchKernelGGL(poly_iou_fused, dim3(nblocks), dim3(BS), 0, stream,
                       pred, tgt, acc, out, n, nblocks, 1.0 / (double)n);
}

// Round 9
// 14.654 us; speedup vs baseline: 1.5179x; 1.5179x over previous
//
#include <hip/hip_runtime.h>
#include <math.h>

// PolyIoULoss closed-form, two-kernel structure (FINAL structure).
// Fusion post-mortems: R4 (release atomics) 73us, R7 (relaxed+single counter)
// 21us, R8 (hierarchical int tree, <=64 contenders) 22us — vs 12.6us for two
// plain dispatches. The memset graph node is itself a fill-kernel dispatch,
// and the post-last-block atomic tail serializes; two dependent kernel nodes
// are strictly cheaper. Do not re-fuse.
//
// Area(P∩T) via Green's theorem: each clipped edge contributes
// (t1-t0)*cross(A,r); cross(A,r) collapses to per-box constants plus offset
// corrections (components of R(psi)*tc). t0/t1 via Liang-Barsky against an
// AABB in the other box's local frame. Branchless; IEEE inf handles parallel
// edges.
// This round: float2-vectorized input loads (two consecutive pairs = 40
// contiguous 8B-aligned bytes = 5 x dwordx2 per array; 12 load insts/thread
// vs 40 scalar) and a single-wave shuffle-only reduce kernel (no LDS/barrier
// on the dependent tail).

#define BS 256
// ITEMS = 2 chunks x 2 consecutive pairs = 4 pairs/thread -> 512 blocks.
#define CHUNKS 2

__device__ __forceinline__ float lb_delta(float Ax, float Ay,
                                          float irx, float iry,
                                          float hw, float hh)
{
    // Liang-Barsky span of segment A + t*r, t in [0,1], vs |x|<=hw,|y|<=hh
    const float tA = (-hw - Ax) * irx;
    const float tB = ( hw - Ax) * irx;
    const float tC = (-hh - Ay) * iry;
    const float tD = ( hh - Ay) * iry;
    const float tx0 = fminf(tA, tB), tx1 = fmaxf(tA, tB);
    const float ty0 = fminf(tC, tD), ty1 = fmaxf(tC, tD);
    const float t0 = fmaxf(fmaxf(tx0, ty0), 0.0f);   // v_max3
    const float t1 = fminf(fminf(tx1, ty1), 1.0f);   // v_min3
    return fmaxf(t1 - t0, 0.0f);
}

__device__ __forceinline__ float pair_loss_v(float pcx, float pcy, float pw,
                                             float ph, float phi,
                                             float qcx, float qcy, float tw,
                                             float th, float psi)
{
    const float tcx = qcx - pcx, tcy = qcy - pcy;   // pred-centered frame

    const float a1 = 0.5f * pw, b1 = 0.5f * ph;
    const float a2 = 0.5f * tw, b2 = 0.5f * th;

    float sphi, cphi, spsi, cpsi;
    __sincosf(phi, &sphi, &cphi);
    __sincosf(psi, &spsi, &cpsi);
    // delta = psi - phi
    const float cd = cpsi * cphi + spsi * sphi;
    const float sd = spsi * cphi - cpsi * sphi;

    // ---- P edges in T-local frame; clipper AABB (a2,b2) ----
    const float Cx = cpsi * tcx - spsi * tcy;
    const float Cy = spsi * tcx + cpsi * tcy;
    const float Xx = a1 * cd,  Xy = a1 * sd;
    const float Yx = -b1 * sd, Yy = b1 * cd;
    const float i0x = __builtin_amdgcn_rcpf(2.0f * Xx);
    const float i0y = __builtin_amdgcn_rcpf(2.0f * Xy);
    const float i1x = __builtin_amdgcn_rcpf(2.0f * Yx);
    const float i1y = __builtin_amdgcn_rcpf(2.0f * Yy);

    const float dP0 = lb_delta(-Xx - Yx - Cx, -Xy - Yy - Cy,  i0x,  i0y, a2, b2);
    const float dP1 = lb_delta( Xx - Yx - Cx,  Xy - Yy - Cy,  i1x,  i1y, a2, b2);
    const float dP2 = lb_delta( Xx + Yx - Cx,  Xy + Yy - Cy, -i0x, -i0y, a2, b2);
    const float dP3 = lb_delta(-Xx + Yx - Cx, -Xy + Yy - Cy, -i1x, -i1y, a2, b2);
    const float sumP = (dP0 + dP1) + (dP2 + dP3);

    // ---- T edges in P-local frame; clipper AABB (a1,b1) ----
    const float C2x = cphi * tcx - sphi * tcy;
    const float C2y = sphi * tcx + cphi * tcy;
    const float Xpx = a2 * cd,  Xpy = -a2 * sd;
    const float Ypx = b2 * sd,  Ypy = b2 * cd;
    const float j0x = __builtin_amdgcn_rcpf(2.0f * Xpx);
    const float j0y = __builtin_amdgcn_rcpf(2.0f * Xpy);
    const float j1x = __builtin_amdgcn_rcpf(2.0f * Ypx);
    const float j1y = __builtin_amdgcn_rcpf(2.0f * Ypy);

    const float dT0 = lb_delta(C2x - Xpx - Ypx, C2y - Xpy - Ypy,  j0x,  j0y, a1, b1);
    const float dT1 = lb_delta(C2x + Xpx - Ypx, C2y + Xpy - Ypy,  j1x,  j1y, a1, b1);
    const float dT2 = lb_delta(C2x + Xpx + Ypx, C2y + Xpy + Ypy, -j0x, -j0y, a1, b1);
    const float dT3 = lb_delta(C2x - Xpx + Ypx, C2y - Xpy + Ypy, -j1x, -j1y, a1, b1);
    const float sumT = (dT0 + dT1) + (dT2 + dT3);

    float area = a1 * b1 * sumP + a2 * b2 * sumT
               - a2 * Cy * (dT0 - dT2) + b2 * Cx * (dT1 - dT3);
    area = fmaxf(area, 0.0f);

    const float A1 = pw * ph, A2 = tw * th;
    const float iou = fmaxf(area / (A1 + A2 - area + 1e-6f), 1e-6f);
    return -__logf(iou);
}

__global__ __launch_bounds__(BS) void poly_iou_kernel(
    const float* __restrict__ pred, const float* __restrict__ tgt,
    float* __restrict__ block_sums, int n)
{
    const int tid = threadIdx.x;
    const int gthreads = gridDim.x * BS;

    float loss = 0.0f;
#pragma unroll
    for (int ch = 0; ch < CHUNKS; ++ch) {
        const int p0 = 2 * (blockIdx.x * BS + tid + ch * gthreads);
        if (p0 + 1 < n) {
            // two consecutive pairs: 40 contiguous bytes, 8B-aligned
            const float2* pp2 = (const float2*)(pred + (long)p0 * 5);
            const float2* tp2 = (const float2*)(tgt  + (long)p0 * 5);
            const float2 pa = pp2[0], pb = pp2[1], pc = pp2[2],
                         pd = pp2[3], pe = pp2[4];
            const float2 ta = tp2[0], tb = tp2[1], tc = tp2[2],
                         td = tp2[3], te = tp2[4];
            loss += pair_loss_v(pa.x, pa.y, pb.x, pb.y, pc.x,
                                ta.x, ta.y, tb.x, tb.y, tc.x);
            loss += pair_loss_v(pc.y, pd.x, pd.y, pe.x, pe.y,
                                tc.y, td.x, td.y, te.x, te.y);
        } else if (p0 < n) {   // odd tail (not hit for n = 524288)
            const float* pp = pred + (long)p0 * 5;
            const float* tp = tgt  + (long)p0 * 5;
            loss += pair_loss_v(pp[0], pp[1], pp[2], pp[3], pp[4],
                                tp[0], tp[1], tp[2], tp[3], tp[4]);
        }
    }

    // block reduction (wave shuffle + tiny LDS), deterministic
#pragma unroll
    for (int off = 32; off > 0; off >>= 1) loss += __shfl_down(loss, off);
    __shared__ float wsum[BS / 64];
    if ((tid & 63) == 0) wsum[tid >> 6] = loss;
    __syncthreads();
    if (tid == 0) {
        float s = 0.0f;
#pragma unroll
        for (int w = 0; w < BS / 64; ++w) s += wsum[w];
        block_sums[blockIdx.x] = s;
    }
}

// Single-wave reduce: no LDS, no barriers on the dependent tail.
__global__ __launch_bounds__(64) void poly_iou_reduce(
    const float* __restrict__ block_sums, int nblocks,
    float* __restrict__ out, double inv_n)
{
    const int tid = threadIdx.x;
    double s = 0.0;
    for (int i = tid; i < nblocks; i += 64)
        s += (double)block_sums[i];
#pragma unroll
    for (int off = 32; off > 0; off >>= 1) s += __shfl_down(s, off);
    if (tid == 0) out[0] = (float)(s * inv_n);
}

extern "C" void kernel_launch(void* const* d_in, const int* in_sizes, int n_in,
                              void* d_out, int out_size, void* d_ws, size_t ws_size,
                              hipStream_t stream) {
    const float* pred = (const float*)d_in[0];
    const float* tgt  = (const float*)d_in[1];
    float* out = (float*)d_out;
    const int n = in_sizes[0] / 5;
    const int pairs_per_block = BS * CHUNKS * 2;
    const int nblocks = (n + pairs_per_block - 1) / pairs_per_block;
    float* bsums = (float*)d_ws;

    hipLaunchKernelGGL(poly_iou_kernel, dim3(nblocks), dim3(BS), 0, stream,
                       pred, tgt, bsums, n);
    hipLaunchKernelGGL(poly_iou_reduce, dim3(1), dim3(64), 0, stream,
                       bsums, nblocks, out, 1.0 / (double)n);
}